// Round 2
// baseline (935.604 us; speedup 1.0000x reference)
//
#include <hip/hip_runtime.h>
#include <hip/hip_bf16.h>

typedef unsigned short u16;
typedef unsigned int u32;
typedef __attribute__((ext_vector_type(4))) float f32x4;
typedef __attribute__((ext_vector_type(8))) short bf16x8;

#define DEVI static __device__ __forceinline__

DEVI u16 f2bf(float f) {
  u32 u = __builtin_bit_cast(u32, f);
  u += 0x7fffu + ((u >> 16) & 1u);
  return (u16)(u >> 16);
}

// ---------------------------------------------------------------------------
// C[M x BN] = A[M x K] @ B[K x BN], B given transposed: Bt[BN][K] (bf16).
// BM=64 rows/block, BK=64, 512 threads = 8 waves, WM=1 x WN=8 (each wave owns
// all 64 rows x TN cols -> B has zero intra-block reuse -> B goes straight
// from L2 to register fragments (no LDS). A (fp32->bf16 or bf16) is reg-staged
// 2 tiles deep, then XOR-swizzled ds_write into a 2-buffer LDS (8x reuse).
// Counted waits only: the barrier asm waits lgkmcnt(0) but leaves all global
// loads in flight (compiler auto-emits counted vmcnt for reg deps).
// EPI: 0 = bf16 transposed write outh[n][m]; 1 = bn2(relu(acc+b1)); 2 = acc+b2
// ---------------------------------------------------------------------------
template<int BN, bool AF32, int EPI>
__global__ __launch_bounds__(512, 2)
void gemm_bt(const void* __restrict__ Ap, const u16* __restrict__ Bt,
             const int K, const int M,
             float* __restrict__ outf, u16* __restrict__ outh,
             const float* __restrict__ e0, const float* __restrict__ e1,
             const float* __restrict__ e2, const float* __restrict__ e3,
             const float* __restrict__ e4)
{
  constexpr int BM = 64, BK = 64;
  constexpr int TN = BN / 8;
  constexpr int MF = BM / 16;          // 4
  constexpr int NF = TN / 16;          // 4 (BN=512) or 1 (BN=128)
  constexpr int ABYTES = BM * BK * 2;  // 8 KiB

  __shared__ char smem[2 * ABYTES];

  const int tid = threadIdx.x;
  const int w = tid >> 6, l = tid & 63;
  const int wn = w;
  const int l15 = l & 15, l4 = l >> 4;

  // XCD-aware swizzle (grid = 256, multiple of 8)
  const int cpx = gridDim.x >> 3;
  const int bid = blockIdx.x;
  const int wg = (bid & 7) * cpx + (bid >> 3);
  const int m0 = wg * BM;

  const int NT = K / BK;

  // A staging map: thread -> (row ar, 16B chunk ac)
  const int ar = tid >> 3, ac = tid & 7;
  const int apos = (ar * 128 + ac * 16) ^ ((ar & 7) << 4);
  const size_t Abase = (size_t)(m0 + ar) * K + (size_t)ac * 8;

  f32x4 acc[MF][NF];
#pragma unroll
  for (int i = 0; i < MF; ++i)
#pragma unroll
    for (int j = 0; j < NF; ++j) acc[i][j] = (f32x4){0.f, 0.f, 0.f, 0.f};

  struct Aregs { f32x4 v0, v1; uint4 h; };
  Aregs R0, R1;
  uint4 BR0[NF][2], BR1[NF][2];

  auto issueA = [&](Aregs& R, int t) {
    if constexpr (AF32) {
      const float* p = (const float*)Ap + Abase + (size_t)t * BK;
      R.v0 = *(const f32x4*)p;
      R.v1 = *(const f32x4*)(p + 4);
    } else {
      const u16* p = (const u16*)Ap + Abase + (size_t)t * BK;
      R.h = *(const uint4*)p;
    }
  };
  auto writeA = [&](int nb, Aregs& R) {
    uint4 pk;
    if constexpr (AF32) {
      pk.x = (u32)f2bf(R.v0[0]) | ((u32)f2bf(R.v0[1]) << 16);
      pk.y = (u32)f2bf(R.v0[2]) | ((u32)f2bf(R.v0[3]) << 16);
      pk.z = (u32)f2bf(R.v1[0]) | ((u32)f2bf(R.v1[1]) << 16);
      pk.w = (u32)f2bf(R.v1[2]) | ((u32)f2bf(R.v1[3]) << 16);
    } else {
      pk = R.h;
    }
    *(uint4*)(smem + nb * ABYTES + apos) = pk;
  };
  auto issueB = [&](uint4 (&BR)[NF][2], int t) {
#pragma unroll
    for (int ni = 0; ni < NF; ++ni)
#pragma unroll
      for (int kk = 0; kk < 2; ++kk) {
        const int n = wn * TN + ni * 16 + l15;
        BR[ni][kk] = *(const uint4*)(Bt + (size_t)n * K + (size_t)t * BK +
                                     kk * 32 + l4 * 8);
      }
  };
  auto compute = [&](int cb, uint4 (&BR)[NF][2]) {
    const char* A = smem + cb * ABYTES;
#pragma unroll
    for (int kk = 0; kk < 2; ++kk) {
      bf16x8 af[MF];
#pragma unroll
      for (int mi = 0; mi < MF; ++mi) {
        const int row = mi * 16 + l15;
        const int off = (row * 128 + kk * 64 + l4 * 16) ^ ((row & 7) << 4);
        af[mi] = *(const bf16x8*)(A + off);
      }
#pragma unroll
      for (int mi = 0; mi < MF; ++mi)
#pragma unroll
        for (int ni = 0; ni < NF; ++ni)
          acc[mi][ni] = __builtin_amdgcn_mfma_f32_16x16x32_bf16(
              af[mi], __builtin_bit_cast(bf16x8, BR[ni][kk]), acc[mi][ni],
              0, 0, 0);
    }
  };

#define BARRIER() asm volatile("s_waitcnt lgkmcnt(0)\ns_barrier" ::: "memory")

  // prologue: tile0 -> LDS buf0; tile1 A in regs; tile0 B frags in flight
  issueA(R0, 0);
  issueA(R1, 1);
  issueB(BR0, 0);
  writeA(0, R0);
  BARRIER();

#define STEP(CUR, R_W, R_I, BR_C, BR_I, T)                                   \
  {                                                                          \
    const bool haveB = (T) + 1 < NT;                                         \
    const bool haveA = (T) + 2 < NT;                                         \
    if (haveB) issueB(BR_I, (T) + 1);                                        \
    if (haveA) issueA(R_I, (T) + 2);                                         \
    compute((CUR), BR_C);                                                    \
    if (haveB) {                                                             \
      writeA((CUR) ^ 1, R_W);                                                \
      BARRIER();                                                             \
    }                                                                        \
  }

  for (int t = 0; t < NT; t += 2) {
    STEP(0, R1, R0, BR0, BR1, t);
    STEP(1, R0, R1, BR1, BR0, t + 1);
  }
#undef STEP
#undef BARRIER

  // epilogue (WM=1: mrow0 from l4)
  const int mrow0 = m0 + l4 * 4;
#pragma unroll
  for (int ni = 0; ni < NF; ++ni) {
    const int n = wn * TN + ni * 16 + l15;
    if constexpr (EPI == 0) {
#pragma unroll
      for (int mi = 0; mi < MF; ++mi) {
        const int m = mrow0 + mi * 16;
        ushort4 o;
        o.x = f2bf(acc[mi][ni][0]);
        o.y = f2bf(acc[mi][ni][1]);
        o.z = f2bf(acc[mi][ni][2]);
        o.w = f2bf(acc[mi][ni][3]);
        *(ushort4*)(outh + (size_t)n * M + m) = o;
      }
    } else if constexpr (EPI == 1) {
      const float b1v = e0[n];
      const float sc = e1[n] * rsqrtf(e4[n] + 1e-5f);
      const float sh = e2[n] - e3[n] * sc;
#pragma unroll
      for (int mi = 0; mi < MF; ++mi)
#pragma unroll
        for (int r = 0; r < 4; ++r) {
          const int m = mrow0 + mi * 16 + r;
          float s = acc[mi][ni][r] + b1v;
          s = fmaxf(s, 0.f);
          outf[(size_t)m * BN + n] = s * sc + sh;
        }
    } else {
      const float b2v = e0[n];
#pragma unroll
      for (int mi = 0; mi < MF; ++mi)
#pragma unroll
        for (int r = 0; r < 4; ++r) {
          const int m = mrow0 + mi * 16 + r;
          outf[(size_t)m * BN + n] = acc[mi][ni][r] + b2v;
        }
    }
  }
}

// ---------------------------------------------------------------------------
// bn1(x) -> bf16, 8 elems/thread
// ---------------------------------------------------------------------------
__global__ __launch_bounds__(256)
void bn1_cast_k(const float* __restrict__ x, const float* __restrict__ g,
                const float* __restrict__ be, const float* __restrict__ rm,
                const float* __restrict__ rv, u16* __restrict__ out)
{
  const size_t i8 = ((size_t)blockIdx.x * 256 + threadIdx.x) * 8;
  const f32x4 v0 = *(const f32x4*)(x + i8);
  const f32x4 v1 = *(const f32x4*)(x + i8 + 4);
  const int f0 = (int)(i8 & 511);
  u16 u[8];
#pragma unroll
  for (int e = 0; e < 8; ++e) {
    const int f = f0 + e;
    const float sc = g[f] * rsqrtf(rv[f] + 1e-5f);
    const float v = (e < 4) ? v0[e] : v1[e - 4];
    u[e] = f2bf((v - rm[f]) * sc + be[f]);
  }
  uint4 o;
  o.x = (u32)u[0] | ((u32)u[1] << 16);
  o.y = (u32)u[2] | ((u32)u[3] << 16);
  o.z = (u32)u[4] | ((u32)u[5] << 16);
  o.w = (u32)u[6] | ((u32)u[7] << 16);
  *(uint4*)(out + i8) = o;
}

// out[n][k] = bf16(in[k][n]); out row length 512, in row length = rowlen
__global__ __launch_bounds__(256)
void tcvt_k(const float* __restrict__ in, u16* __restrict__ out, int rowlen)
{
  const int o = blockIdx.x * 256 + threadIdx.x;
  const int n = o >> 9, k = o & 511;
  out[o] = f2bf(in[(size_t)k * rowlen + n]);
}

// ---------------------------------------------------------------------------
extern "C" void kernel_launch(void* const* d_in, const int* in_sizes, int n_in,
                              void* d_out, int out_size, void* d_ws, size_t ws_size,
                              hipStream_t stream)
{
  const float* x   = (const float*)d_in[0];
  const float* a   = (const float*)d_in[1];
  const float* w1  = (const float*)d_in[2];
  const float* b1  = (const float*)d_in[3];
  const float* w2  = (const float*)d_in[4];
  const float* b2  = (const float*)d_in[5];
  const float* g1  = (const float*)d_in[6];
  const float* be1 = (const float*)d_in[7];
  const float* rm1 = (const float*)d_in[8];
  const float* rv1 = (const float*)d_in[9];
  const float* g2  = (const float*)d_in[10];
  const float* be2 = (const float*)d_in[11];
  const float* rm2 = (const float*)d_in[12];
  const float* rv2 = (const float*)d_in[13];

  constexpr int N = 16384, F = 512, H = 512, C = 128;
  float* out_x1 = (float*)d_out;                    // [N][C]
  float* out_x2 = (float*)d_out + (size_t)N * C;    // [N][H]

  char* wsp = (char*)d_ws;
  u16* xb  = (u16*)wsp;  wsp += (size_t)N * F * 2;  // bn1(x) bf16
  u16* t_t = (u16*)wsp;  wsp += (size_t)H * N * 2;  // (bn1x@w1)^T
  u16* z_t = (u16*)wsp;  wsp += (size_t)C * N * 2;  // (x2@w2)^T
  u16* w1t = (u16*)wsp;  wsp += (size_t)H * F * 2;  // w1^T bf16
  u16* w2t = (u16*)wsp;  wsp += (size_t)C * H * 2;  // w2^T bf16

  // k0: elementwise prep
  bn1_cast_k<<<(N * F / 8) / 256, 256, 0, stream>>>(x, g1, be1, rm1, rv1, xb);
  tcvt_k<<<(F * H) / 256, 256, 0, stream>>>(w1, w1t, H);   // w1t[h][f]
  tcvt_k<<<(H * C) / 256, 256, 0, stream>>>(w2, w2t, C);   // w2t[c][h]

  // k1: t = bn1x @ w1 -> t_t[h][node] bf16
  gemm_bt<512, false, 0><<<N / 64, 512, 0, stream>>>(
      xb, w1t, F, N, nullptr, t_t, nullptr, nullptr, nullptr, nullptr, nullptr);

  // k2: x2 = bn2(relu(a @ t + b1)) -> out_x2 fp32
  gemm_bt<512, true, 1><<<N / 64, 512, 0, stream>>>(
      a, t_t, N, N, out_x2, nullptr, b1, g2, be2, rm2, rv2);

  // k3: z = x2 @ w2 -> z_t[c][node] bf16
  gemm_bt<128, true, 0><<<N / 64, 512, 0, stream>>>(
      out_x2, w2t, H, N, nullptr, z_t, nullptr, nullptr, nullptr, nullptr, nullptr);

  // k4: x1 = a @ z + b2 -> out_x1 fp32
  gemm_bt<128, true, 2><<<N / 64, 512, 0, stream>>>(
      a, z_t, N, N, out_x1, nullptr, b2, nullptr, nullptr, nullptr, nullptr);
}

// Round 3
// 916.286 us; speedup vs baseline: 1.0211x; 1.0211x over previous
//
#include <hip/hip_runtime.h>
#include <hip/hip_bf16.h>

typedef unsigned short u16;
typedef unsigned int u32;
typedef __attribute__((ext_vector_type(4))) float f32x4;
typedef __attribute__((ext_vector_type(8))) short bf16x8;

#define DEVI static __device__ __forceinline__

DEVI u16 f2bf(float f) {
  u32 u = __builtin_bit_cast(u32, f);
  u += 0x7fffu + ((u >> 16) & 1u);
  return (u16)(u >> 16);
}

DEVI void gload_lds16(const void* g, void* l) {
  __builtin_amdgcn_global_load_lds(
      (const __attribute__((address_space(1))) u32*)g,
      (__attribute__((address_space(3))) u32*)l, 16, 0, 0);
}

template<int N> DEVI void wait_vm() {
  if constexpr (N == 3)       asm volatile("s_waitcnt vmcnt(3)" ::: "memory");
  else if constexpr (N == 4)  asm volatile("s_waitcnt vmcnt(4)" ::: "memory");
  else if constexpr (N == 9)  asm volatile("s_waitcnt vmcnt(9)" ::: "memory");
  else if constexpr (N == 10) asm volatile("s_waitcnt vmcnt(10)" ::: "memory");
  else                        asm volatile("s_waitcnt vmcnt(0)" ::: "memory");
}
DEVI void lgkm_barrier() {
  asm volatile("s_waitcnt lgkmcnt(0)\n\ts_barrier" ::: "memory");
}

// ---------------------------------------------------------------------------
// C[M x BN] = A[M x K] @ Bt[BN][K]^T (bf16 Bt). BM=64, BK=64, 512 thr, 8 waves
// WM=1 x WN=8. B: per-wave slice staged via global_load_lds (inverse-swizzled
// global source, linear LDS dest) -> B readiness is wave-local vmcnt, no
// barrier. A: fp32(or bf16) reg-prefetched 2 tiles deep, cvt->bf16, XOR-
// swizzled ds_write. One lgkmcnt(0)+s_barrier per step; vmcnt counted (never
// drained). EPI: 0 = bf16 transposed outh[n][m]; 1 = bn2(relu(acc+b1)) fp32;
// 2 = acc+b2 fp32.
// ---------------------------------------------------------------------------
template<int BN, bool AF32, int EPI>
__global__ __launch_bounds__(512, 2)
void gemm_bt(const void* __restrict__ Ap, const u16* __restrict__ Bt,
             const int K, const int M,
             float* __restrict__ outf, u16* __restrict__ outh,
             const float* __restrict__ e0, const float* __restrict__ e1,
             const float* __restrict__ e2, const float* __restrict__ e3,
             const float* __restrict__ e4)
{
  constexpr int BM = 64, BK = 64;
  constexpr int TN = BN / 8;           // 64 | 16
  constexpr int MF = 4, NF = TN / 16;  // 4x(4|1) fragments per wave
  constexpr int ABYTES = BM * BK * 2;  // 8 KiB
  constexpr int SLICE = TN * BK * 2;   // 8 KiB | 2 KiB per wave
  constexpr int LB = SLICE / 1024;     // gload_lds per thread: 8 | 2
  constexpr int LA = AF32 ? 2 : 1;
  constexpr int VM = LB + LA;

  __shared__ char smem[2 * ABYTES + 16 * SLICE];

  const int tid = threadIdx.x;
  const int w = tid >> 6, l = tid & 63;
  const int l15 = l & 15, l4 = l >> 4;

  const int cpx = gridDim.x >> 3;
  const int bid = blockIdx.x;
  const int wg = (bid & 7) * cpx + (bid >> 3);
  const int m0 = wg * BM;
  const int NT = K / BK;

  const int ar = tid >> 3, ac = tid & 7;
  const int apos = (ar * 128 + ac * 16) ^ ((ar & 7) << 4);
  const size_t Abase = (size_t)(m0 + ar) * K + (size_t)ac * 8;

  char* const bslice = smem + 2 * ABYTES + w * SLICE;

  f32x4 acc[MF][NF];
#pragma unroll
  for (int i = 0; i < MF; ++i)
#pragma unroll
    for (int j = 0; j < NF; ++j) acc[i][j] = (f32x4){0.f, 0.f, 0.f, 0.f};

  struct Aregs { f32x4 v0, v1; uint4 h; };
  Aregs RA, RB;

  auto issueA = [&](Aregs& R, int t) {
    if constexpr (AF32) {
      const float* p = (const float*)Ap + Abase + (size_t)t * BK;
      R.v0 = *(const f32x4*)p;
      R.v1 = *(const f32x4*)(p + 4);
    } else {
      const u16* p = (const u16*)Ap + Abase + (size_t)t * BK;
      R.h = *(const uint4*)p;
    }
  };
  auto writeA = [&](int nb, Aregs& R) {
    uint4 pk;
    if constexpr (AF32) {
      pk.x = (u32)f2bf(R.v0[0]) | ((u32)f2bf(R.v0[1]) << 16);
      pk.y = (u32)f2bf(R.v0[2]) | ((u32)f2bf(R.v0[3]) << 16);
      pk.z = (u32)f2bf(R.v1[0]) | ((u32)f2bf(R.v1[1]) << 16);
      pk.w = (u32)f2bf(R.v1[2]) | ((u32)f2bf(R.v1[3]) << 16);
    } else {
      pk = R.h;
    }
    *(uint4*)(smem + nb * ABYTES + apos) = pk;
  };
  auto issueB = [&](int nb, int t) {
    const char* bsrc = (const char*)Bt + (size_t)t * (BK * 2);
    char* bd = bslice + nb * (8 * SLICE);
#pragma unroll
    for (int i = 0; i < LB; ++i) {
      const int p = i * 1024 + l * 16;
      const int nl = p >> 7;
      const int colq = (p & 127) ^ ((nl & 7) << 4);
      gload_lds16(bsrc + (size_t)(w * TN + nl) * (2 * (size_t)K) + colq,
                  bd + i * 1024);
    }
  };
  auto compute = [&](int cb) {
    const char* A = smem + cb * ABYTES;
    const char* Bs = bslice + cb * (8 * SLICE);
    bf16x8 af[2][MF];
    uint4 bfr[2][NF];
#pragma unroll
    for (int kk = 0; kk < 2; ++kk) {
#pragma unroll
      for (int mi = 0; mi < MF; ++mi) {
        const int row = mi * 16 + l15;
        const int off = (row * 128 + kk * 64 + l4 * 16) ^ ((row & 7) << 4);
        af[kk][mi] = *(const bf16x8*)(A + off);
      }
#pragma unroll
      for (int ni = 0; ni < NF; ++ni) {
        const int nl = ni * 16 + l15;
        const int off = (nl * 128 + kk * 64 + l4 * 16) ^ ((nl & 7) << 4);
        bfr[kk][ni] = *(const uint4*)(Bs + off);
      }
    }
    __builtin_amdgcn_s_setprio(1);
#pragma unroll
    for (int kk = 0; kk < 2; ++kk)
#pragma unroll
      for (int mi = 0; mi < MF; ++mi)
#pragma unroll
        for (int ni = 0; ni < NF; ++ni)
          acc[mi][ni] = __builtin_amdgcn_mfma_f32_16x16x32_bf16(
              af[kk][mi], __builtin_bit_cast(bf16x8, bfr[kk][ni]),
              acc[mi][ni], 0, 0, 0);
    __builtin_amdgcn_s_setprio(0);
  };

  // prologue: A(0),A(1) in regs; B(0) in flight; A(0)->LDS buf0
  issueA(RA, 0);
  issueA(RB, 1);
  issueB(0, 0);
  writeA(0, RA);       // compiler waits only RA's loads (B(0) stays in flight)
  lgkm_barrier();

#define STEP(CUR, RW, RI, T)                                                 \
  {                                                                          \
    const int tB = ((T) + 1 < NT) ? (T) + 1 : NT - 1;                        \
    const int tA = ((T) + 2 < NT) ? (T) + 2 : NT - 1;                        \
    issueB((CUR) ^ 1, tB);                                                   \
    issueA(RI, tA);                                                          \
    wait_vm<VM>();                                                           \
    compute(CUR);                                                            \
    writeA((CUR) ^ 1, RW);                                                   \
    lgkm_barrier();                                                          \
  }

  for (int t = 0; t < NT; t += 2) {
    STEP(0, RB, RA, t);
    STEP(1, RA, RB, t + 1);
  }
#undef STEP

  // epilogue
  const int mrow0 = m0 + l4 * 4;
#pragma unroll
  for (int ni = 0; ni < NF; ++ni) {
    const int n = w * TN + ni * 16 + l15;
    if constexpr (EPI == 0) {
#pragma unroll
      for (int mi = 0; mi < MF; ++mi) {
        const int m = mrow0 + mi * 16;
        ushort4 o;
        o.x = f2bf(acc[mi][ni][0]);
        o.y = f2bf(acc[mi][ni][1]);
        o.z = f2bf(acc[mi][ni][2]);
        o.w = f2bf(acc[mi][ni][3]);
        *(ushort4*)(outh + (size_t)n * M + m) = o;
      }
    } else if constexpr (EPI == 1) {
      const float b1v = e0[n];
      const float sc = e1[n] * rsqrtf(e4[n] + 1e-5f);
      const float sh = e2[n] - e3[n] * sc;
#pragma unroll
      for (int mi = 0; mi < MF; ++mi)
#pragma unroll
        for (int r = 0; r < 4; ++r) {
          const int m = mrow0 + mi * 16 + r;
          float s = acc[mi][ni][r] + b1v;
          s = fmaxf(s, 0.f);
          outf[(size_t)m * BN + n] = s * sc + sh;
        }
    } else {
      const float b2v = e0[n];
#pragma unroll
      for (int mi = 0; mi < MF; ++mi)
#pragma unroll
        for (int r = 0; r < 4; ++r) {
          const int m = mrow0 + mi * 16 + r;
          outf[(size_t)m * BN + n] = acc[mi][ni][r] + b2v;
        }
    }
  }
}

// ---------------------------------------------------------------------------
__global__ __launch_bounds__(256)
void bn1_cast_k(const float* __restrict__ x, const float* __restrict__ g,
                const float* __restrict__ be, const float* __restrict__ rm,
                const float* __restrict__ rv, u16* __restrict__ out)
{
  const size_t i8 = ((size_t)blockIdx.x * 256 + threadIdx.x) * 8;
  const f32x4 v0 = *(const f32x4*)(x + i8);
  const f32x4 v1 = *(const f32x4*)(x + i8 + 4);
  const int f0 = (int)(i8 & 511);
  u16 u[8];
#pragma unroll
  for (int e = 0; e < 8; ++e) {
    const int f = f0 + e;
    const float sc = g[f] * rsqrtf(rv[f] + 1e-5f);
    const float v = (e < 4) ? v0[e] : v1[e - 4];
    u[e] = f2bf((v - rm[f]) * sc + be[f]);
  }
  uint4 o;
  o.x = (u32)u[0] | ((u32)u[1] << 16);
  o.y = (u32)u[2] | ((u32)u[3] << 16);
  o.z = (u32)u[4] | ((u32)u[5] << 16);
  o.w = (u32)u[6] | ((u32)u[7] << 16);
  *(uint4*)(out + i8) = o;
}

__global__ __launch_bounds__(256)
void tcvt_k(const float* __restrict__ in, u16* __restrict__ out, int rowlen)
{
  const int o = blockIdx.x * 256 + threadIdx.x;
  const int n = o >> 9, k = o & 511;
  out[o] = f2bf(in[(size_t)k * rowlen + n]);
}

// ---------------------------------------------------------------------------
extern "C" void kernel_launch(void* const* d_in, const int* in_sizes, int n_in,
                              void* d_out, int out_size, void* d_ws, size_t ws_size,
                              hipStream_t stream)
{
  const float* x   = (const float*)d_in[0];
  const float* a   = (const float*)d_in[1];
  const float* w1  = (const float*)d_in[2];
  const float* b1  = (const float*)d_in[3];
  const float* w2  = (const float*)d_in[4];
  const float* b2  = (const float*)d_in[5];
  const float* g1  = (const float*)d_in[6];
  const float* be1 = (const float*)d_in[7];
  const float* rm1 = (const float*)d_in[8];
  const float* rv1 = (const float*)d_in[9];
  const float* g2  = (const float*)d_in[10];
  const float* be2 = (const float*)d_in[11];
  const float* rm2 = (const float*)d_in[12];
  const float* rv2 = (const float*)d_in[13];

  constexpr int N = 16384, F = 512, H = 512, C = 128;
  float* out_x1 = (float*)d_out;                    // [N][C]
  float* out_x2 = (float*)d_out + (size_t)N * C;    // [N][H]

  char* wsp = (char*)d_ws;
  u16* xb  = (u16*)wsp;  wsp += (size_t)N * F * 2;  // bn1(x) bf16
  u16* t_t = (u16*)wsp;  wsp += (size_t)H * N * 2;  // (bn1x@w1)^T
  u16* z_t = (u16*)wsp;  wsp += (size_t)C * N * 2;  // (x2@w2)^T
  u16* w1t = (u16*)wsp;  wsp += (size_t)H * F * 2;  // w1^T bf16
  u16* w2t = (u16*)wsp;  wsp += (size_t)C * H * 2;  // w2^T bf16

  bn1_cast_k<<<(N * F / 8) / 256, 256, 0, stream>>>(x, g1, be1, rm1, rv1, xb);
  tcvt_k<<<(F * H) / 256, 256, 0, stream>>>(w1, w1t, H);   // w1t[h][f]
  tcvt_k<<<(H * C) / 256, 256, 0, stream>>>(w2, w2t, C);   // w2t[c][h]

  // k1: t = bn1x @ w1 -> t_t[h][node] bf16
  gemm_bt<512, false, 0><<<N / 64, 512, 0, stream>>>(
      xb, w1t, F, N, nullptr, t_t, nullptr, nullptr, nullptr, nullptr, nullptr);

  // k2: x2 = bn2(relu(a @ t + b1)) -> out_x2 fp32
  gemm_bt<512, true, 1><<<N / 64, 512, 0, stream>>>(
      a, t_t, N, N, out_x2, nullptr, b1, g2, be2, rm2, rv2);

  // k3: z = x2 @ w2 -> z_t[c][node] bf16
  gemm_bt<128, true, 0><<<N / 64, 512, 0, stream>>>(
      out_x2, w2t, H, N, nullptr, z_t, nullptr, nullptr, nullptr, nullptr, nullptr);

  // k4: x1 = a @ z + b2 -> out_x1 fp32
  gemm_bt<128, true, 2><<<N / 64, 512, 0, stream>>>(
      a, z_t, N, N, out_x1, nullptr, b2, nullptr, nullptr, nullptr, nullptr);
}

// Round 4
// 890.063 us; speedup vs baseline: 1.0512x; 1.0295x over previous
//
#include <hip/hip_runtime.h>
#include <hip/hip_bf16.h>

typedef unsigned short u16;
typedef unsigned int u32;
typedef __attribute__((ext_vector_type(4))) float f32x4;
typedef __attribute__((ext_vector_type(8))) short bf16x8;

#define DEVI static __device__ __forceinline__

DEVI u16 f2bf(float f) {
  u32 u = __builtin_bit_cast(u32, f);
  u += 0x7fffu + ((u >> 16) & 1u);
  return (u16)(u >> 16);
}

DEVI void gload_lds16(const void* g, void* l) {
  __builtin_amdgcn_global_load_lds(
      (const __attribute__((address_space(1))) u32*)g,
      (__attribute__((address_space(3))) u32*)l, 16, 0, 0);
}

template<int N> DEVI void wait_vm() {
  if constexpr (N == 3)      asm volatile("s_waitcnt vmcnt(3)" ::: "memory");
  else if constexpr (N == 4) asm volatile("s_waitcnt vmcnt(4)" ::: "memory");
  else if constexpr (N == 6) asm volatile("s_waitcnt vmcnt(6)" ::: "memory");
  else if constexpr (N == 9) asm volatile("s_waitcnt vmcnt(9)" ::: "memory");
  else                       asm volatile("s_waitcnt vmcnt(0)" ::: "memory");
}
DEVI void lgkm_barrier() {
  asm volatile("s_waitcnt lgkmcnt(0)\n\ts_barrier" ::: "memory");
}

// ---------------------------------------------------------------------------
// C[M x BN] = A[M x K] @ Bt[BN][K]^T (bf16 Bt). 512 thr = 8 waves, 1x8 wave
// grid (each wave: all BM rows x TN=BN/8 cols). A reg-staged (fp32->bf16 cvt)
// -> swizzled LDS (dbuf); B per-wave slice via global_load_lds (inverse-
// swizzled source). Counted vmcnt; lgkmcnt(0)+s_barrier per step only.
// KSPLIT: grid = (M/BM)*KSPLIT blocks; k-chunk kc owns K range
// [kc*klen, (kc+1)*klen). EPI: 0 = bf16 transposed outh[n][M]+m;
// 3 = fp32 partial store to outf + kc*M*BN.
// ---------------------------------------------------------------------------
template<int BM, int BN, int BK, bool AF32, int EPI, int KSPLIT>
__global__ __launch_bounds__(512, 2)
void gemm_bt(const void* __restrict__ Ap, const u16* __restrict__ Bt,
             const int Kfull, const int klen, const int M,
             float* __restrict__ outf, u16* __restrict__ outh)
{
  constexpr int TN = BN / 8;
  constexpr int MF = BM / 16, NF = TN / 16, KK = BK / 32;
  constexpr int ABYTES = BM * BK * 2;
  constexpr int SLICE = TN * BK * 2;
  constexpr int LB = SLICE / 1024;       // gload_lds per lane
  constexpr int LA = AF32 ? 2 : 1;       // A global loads per thread
  constexpr int VM = LA + LB;
  constexpr int RB = BK * 2;             // LDS row bytes
  static_assert(BM * BK / 8 == 512 * (BK == 64 ? 1 : 1), "one A chunk/thread");

  __shared__ char smem[2 * ABYTES + 16 * SLICE];

  const int tid = threadIdx.x;
  const int w = tid >> 6, l = tid & 63;
  const int l15 = l & 15, l4 = l >> 4;

  const int cpx = gridDim.x >> 3;
  const int bid = blockIdx.x;
  const int wg = (bid & 7) * cpx + (bid >> 3);
  const int mt = gridDim.x / KSPLIT;
  const int kc = (KSPLIT == 2 && wg >= mt) ? 1 : 0;
  const int mtile = wg - kc * mt;
  const int m0 = mtile * BM;
  const int k0 = kc * klen;
  const int NT = klen / BK;

  auto off = [&](int row, int q) -> int {
    if constexpr (BK == 64) return row * 128 + ((q ^ (row & 7)) << 4);
    else                    return row * 64 + ((q ^ ((row >> 1) & 3)) << 4);
  };

  // A staging: one 8-element chunk per thread
  const int ar = (BK == 64) ? (tid >> 3) : (tid >> 2);
  const int ac = (BK == 64) ? (tid & 7) : (tid & 3);
  const int apos = off(ar, ac);
  const size_t Abase = (size_t)(m0 + ar) * Kfull + k0 + ac * 8;

  char* const bslice = smem + 2 * ABYTES + w * SLICE;

  f32x4 acc[MF][NF];
#pragma unroll
  for (int i = 0; i < MF; ++i)
#pragma unroll
    for (int j = 0; j < NF; ++j) acc[i][j] = (f32x4){0.f, 0.f, 0.f, 0.f};

  struct Aregs { f32x4 v0, v1; uint4 h; };
  Aregs RA;

  auto issueA = [&](int t) {
    if constexpr (AF32) {
      const float* p = (const float*)Ap + Abase + (size_t)t * BK;
      RA.v0 = *(const f32x4*)p;
      RA.v1 = *(const f32x4*)(p + 4);
    } else {
      const u16* p = (const u16*)Ap + Abase + (size_t)t * BK;
      RA.h = *(const uint4*)p;
    }
  };
  auto writeA = [&](int nb) {
    uint4 pk;
    if constexpr (AF32) {
      pk.x = (u32)f2bf(RA.v0[0]) | ((u32)f2bf(RA.v0[1]) << 16);
      pk.y = (u32)f2bf(RA.v0[2]) | ((u32)f2bf(RA.v0[3]) << 16);
      pk.z = (u32)f2bf(RA.v1[0]) | ((u32)f2bf(RA.v1[1]) << 16);
      pk.w = (u32)f2bf(RA.v1[2]) | ((u32)f2bf(RA.v1[3]) << 16);
    } else {
      pk = RA.h;
    }
    *(uint4*)(smem + nb * ABYTES + apos) = pk;
  };
  auto issueB = [&](int nb, int t) {
    const char* bsrc = (const char*)Bt + (size_t)(w * TN) * ((size_t)Kfull * 2) +
                       (size_t)(k0 + t * BK) * 2;
    char* bd = bslice + nb * (8 * SLICE);
#pragma unroll
    for (int i = 0; i < LB; ++i) {
      const int p = i * 1024 + l * 16;
      const int nl = p / RB;
      const int chp = (p % RB) >> 4;
      const int q = (BK == 64) ? (chp ^ (nl & 7)) : (chp ^ ((nl >> 1) & 3));
      gload_lds16(bsrc + (size_t)nl * ((size_t)Kfull * 2) + q * 16,
                  bd + i * 1024);
    }
  };
  auto compute = [&](int cb) {
    const char* A = smem + cb * ABYTES;
    const char* Bs = bslice + cb * (8 * SLICE);
#pragma unroll
    for (int kk = 0; kk < KK; ++kk) {
      bf16x8 af[MF];
      uint4 bfr[NF];
#pragma unroll
      for (int mi = 0; mi < MF; ++mi)
        af[mi] = *(const bf16x8*)(A + off(mi * 16 + l15, kk * 4 + l4));
#pragma unroll
      for (int ni = 0; ni < NF; ++ni)
        bfr[ni] = *(const uint4*)(Bs + off(ni * 16 + l15, kk * 4 + l4));
      __builtin_amdgcn_s_setprio(1);
#pragma unroll
      for (int mi = 0; mi < MF; ++mi)
#pragma unroll
        for (int ni = 0; ni < NF; ++ni)
          acc[mi][ni] = __builtin_amdgcn_mfma_f32_16x16x32_bf16(
              af[mi], __builtin_bit_cast(bf16x8, bfr[ni]), acc[mi][ni],
              0, 0, 0);
      __builtin_amdgcn_s_setprio(0);
    }
  };

  // prologue: A(0) regs -> LDS buf0 (waits only A loads); B(0) stays in flight
  issueA(0);
  issueB(0, 0);
  writeA(0);
  lgkm_barrier();

  for (int t = 0; t < NT; ++t) {
    const int cur = t & 1, nxt = cur ^ 1;
    const int tn = (t + 1 < NT) ? t + 1 : NT - 1;
    issueA(tn);           // A first (oldest) so writeA's reg-wait = vmcnt(LB)
    issueB(nxt, tn);
    wait_vm<VM>();        // drains B(t) issued last step; keeps A/B(t+1) going
    compute(cur);
    writeA(nxt);          // implicit vmcnt(LB): waits A(t+1), B(t+1) in flight
    lgkm_barrier();
  }

  // epilogue
  const int mrow0 = m0 + l4 * 4;
#pragma unroll
  for (int ni = 0; ni < NF; ++ni) {
    const int n = w * TN + ni * 16 + l15;
    if constexpr (EPI == 0) {
#pragma unroll
      for (int mi = 0; mi < MF; ++mi) {
        const int m = mrow0 + mi * 16;
        ushort4 o;
        o.x = f2bf(acc[mi][ni][0]);
        o.y = f2bf(acc[mi][ni][1]);
        o.z = f2bf(acc[mi][ni][2]);
        o.w = f2bf(acc[mi][ni][3]);
        *(ushort4*)(outh + (size_t)n * M + m) = o;
      }
    } else {
      float* Pout = outf + (size_t)kc * ((size_t)M * BN);
#pragma unroll
      for (int mi = 0; mi < MF; ++mi)
#pragma unroll
        for (int r = 0; r < 4; ++r) {
          const int m = mrow0 + mi * 16 + r;
          Pout[(size_t)m * BN + n] = acc[mi][ni][r];
        }
    }
  }
}

// ---------------------------------------------------------------------------
__global__ __launch_bounds__(256)
void bn1_cast_k(const float* __restrict__ x, const float* __restrict__ g,
                const float* __restrict__ be, const float* __restrict__ rm,
                const float* __restrict__ rv, u16* __restrict__ out)
{
  const size_t i8 = ((size_t)blockIdx.x * 256 + threadIdx.x) * 8;
  const f32x4 v0 = *(const f32x4*)(x + i8);
  const f32x4 v1 = *(const f32x4*)(x + i8 + 4);
  const int f0 = (int)(i8 & 511);
  u16 u[8];
#pragma unroll
  for (int e = 0; e < 8; ++e) {
    const int f = f0 + e;
    const float sc = g[f] * rsqrtf(rv[f] + 1e-5f);
    const float v = (e < 4) ? v0[e] : v1[e - 4];
    u[e] = f2bf((v - rm[f]) * sc + be[f]);
  }
  uint4 o;
  o.x = (u32)u[0] | ((u32)u[1] << 16);
  o.y = (u32)u[2] | ((u32)u[3] << 16);
  o.z = (u32)u[4] | ((u32)u[5] << 16);
  o.w = (u32)u[6] | ((u32)u[7] << 16);
  *(uint4*)(out + i8) = o;
}

__global__ __launch_bounds__(256)
void tcvt_k(const float* __restrict__ in, u16* __restrict__ out, int rowlen)
{
  const int o = blockIdx.x * 256 + threadIdx.x;
  const int n = o >> 9, k = o & 511;
  out[o] = f2bf(in[(size_t)k * rowlen + n]);
}

// x2 = bn2(relu(P0 + P1 + b1)) ; row length 512
__global__ __launch_bounds__(256)
void comb_bn_k(const float* __restrict__ P0, const float* __restrict__ P1,
               const float* __restrict__ b1, const float* __restrict__ g2,
               const float* __restrict__ be2, const float* __restrict__ rm2,
               const float* __restrict__ rv2, float* __restrict__ out)
{
  const size_t i4 = ((size_t)blockIdx.x * 256 + threadIdx.x) * 4;
  const f32x4 p0 = *(const f32x4*)(P0 + i4);
  const f32x4 p1 = *(const f32x4*)(P1 + i4);
  const int n0 = (int)(i4 & 511);
  f32x4 o;
#pragma unroll
  for (int e = 0; e < 4; ++e) {
    const int f = n0 + e;
    float s = p0[e] + p1[e] + b1[f];
    s = fmaxf(s, 0.f);
    const float sc = g2[f] * rsqrtf(rv2[f] + 1e-5f);
    o[e] = s * sc + (be2[f] - rm2[f] * sc);
  }
  *(f32x4*)(out + i4) = o;
}

// x1 = P0 + P1 + b2 ; row length 128
__global__ __launch_bounds__(256)
void comb_k(const float* __restrict__ P0, const float* __restrict__ P1,
            const float* __restrict__ b2, float* __restrict__ out)
{
  const size_t i4 = ((size_t)blockIdx.x * 256 + threadIdx.x) * 4;
  const f32x4 p0 = *(const f32x4*)(P0 + i4);
  const f32x4 p1 = *(const f32x4*)(P1 + i4);
  const int n0 = (int)(i4 & 127);
  f32x4 o;
#pragma unroll
  for (int e = 0; e < 4; ++e) o[e] = p0[e] + p1[e] + b2[n0 + e];
  *(f32x4*)(out + i4) = o;
}

// ---------------------------------------------------------------------------
extern "C" void kernel_launch(void* const* d_in, const int* in_sizes, int n_in,
                              void* d_out, int out_size, void* d_ws, size_t ws_size,
                              hipStream_t stream)
{
  const float* x   = (const float*)d_in[0];
  const float* a   = (const float*)d_in[1];
  const float* w1  = (const float*)d_in[2];
  const float* b1  = (const float*)d_in[3];
  const float* w2  = (const float*)d_in[4];
  const float* b2  = (const float*)d_in[5];
  const float* g1  = (const float*)d_in[6];
  const float* be1 = (const float*)d_in[7];
  const float* rm1 = (const float*)d_in[8];
  const float* rv1 = (const float*)d_in[9];
  const float* g2  = (const float*)d_in[10];
  const float* be2 = (const float*)d_in[11];
  const float* rm2 = (const float*)d_in[12];
  const float* rv2 = (const float*)d_in[13];

  constexpr int N = 16384, F = 512, H = 512, C = 128;
  float* out_x1 = (float*)d_out;                    // [N][C]
  float* out_x2 = (float*)d_out + (size_t)N * C;    // [N][H]

  char* wsp = (char*)d_ws;
  u16* xb  = (u16*)wsp;  wsp += (size_t)N * F * 2;        // bn1(x) bf16
  u16* t_t = (u16*)wsp;  wsp += (size_t)H * N * 2;        // (bn1x@w1)^T
  u16* z_t = (u16*)wsp;  wsp += (size_t)C * N * 2;        // (x2@w2)^T
  u16* w1t = (u16*)wsp;  wsp += (size_t)H * F * 2;        // w1^T
  u16* w2t = (u16*)wsp;  wsp += (size_t)C * H * 2;        // w2^T
  float* P2 = (float*)wsp; wsp += (size_t)2 * N * H * 4;  // k2 partials (2x)
  float* P4 = (float*)wsp; wsp += (size_t)2 * N * C * 4;  // k4 partials (2x)

  bn1_cast_k<<<(N * F / 8) / 256, 256, 0, stream>>>(x, g1, be1, rm1, rv1, xb);
  tcvt_k<<<(F * H) / 256, 256, 0, stream>>>(w1, w1t, H);   // w1t[h][f]
  tcvt_k<<<(H * C) / 256, 256, 0, stream>>>(w2, w2t, C);   // w2t[c][h]

  // k1: t = bn1x @ w1 -> t_t[h][node]
  gemm_bt<64, 512, 64, false, 0, 1><<<N / 64, 512, 0, stream>>>(
      xb, w1t, F, F, N, nullptr, t_t);

  // k2a: partial (a @ t), BM=128, K split in 2 -> P2
  gemm_bt<128, 512, 32, true, 3, 2><<<(N / 128) * 2, 512, 0, stream>>>(
      a, t_t, N, N / 2, N, P2, nullptr);

  // k2b: x2 = bn2(relu(P2a + P2b + b1))
  comb_bn_k<<<(N * H / 4) / 256, 256, 0, stream>>>(
      P2, P2 + (size_t)N * H, b1, g2, be2, rm2, rv2, out_x2);

  // k3: z = x2 @ w2 -> z_t[c][node]
  gemm_bt<64, 128, 64, true, 0, 1><<<N / 64, 512, 0, stream>>>(
      out_x2, w2t, H, H, N, nullptr, z_t);

  // k4a: partial (a @ z), BM=128, K split in 2 -> P4
  gemm_bt<128, 128, 32, true, 3, 2><<<(N / 128) * 2, 512, 0, stream>>>(
      a, z_t, N, N / 2, N, P4, nullptr);

  // k4b: x1 = P4a + P4b + b2
  comb_k<<<(N * C / 4) / 256, 256, 0, stream>>>(
      P4, P4 + (size_t)N * C, b2, out_x1);
}